// Round 20
// baseline (722.956 us; speedup 1.0000x reference)
//
#include <hip/hip_runtime.h>
#include <hip/hip_bf16.h>

#define NTOK 8192
#define DM 1024
#define DFF 4096
#define NE 8
#define MAXT 136  // max 128-row tiles: 16384/128 + 8 partials

typedef __attribute__((ext_vector_type(8))) short bf16x8;
typedef __attribute__((ext_vector_type(4))) float f32x4;

__device__ __forceinline__ ushort f2bf(float f) {
  __hip_bfloat16 h = __float2bfloat16(f);
  return *reinterpret_cast<ushort*>(&h);
}

// ---- pack W [e][K][N] fp32 -> Wp chunks keyed (e*(N/128)+nT)*(K/64)+kt of
// ---- [row128][64 ushort], swizzle baked: pos p holds col p^((row&7)<<3).
// ---- v2: zero-LDS wave-transpose. Wave = one 64K x 64N tile; instr k reads
// ---- 256B coalesced (lane = N-col); lane ends holding its output row's 64
// ---- K-vals in regs; 8x dwordx4 stores with the group-XOR applied by store
// ---- order. No LDS / no barriers (R19's LDS+sync version measured ~3x its
// ---- own BW roofline).
template <int K, int N>
__global__ __launch_bounds__(256, 8) void pack_w(const float* __restrict__ in,
                                                 ushort* __restrict__ outp) {
  constexpr int NT64 = N / 64, KT = K / 64;
  const int gw = (blockIdx.x * 256 + threadIdx.x) >> 6;  // global wave id
  const int lane = threadIdx.x & 63;
  const int nT64 = gw % NT64;
  const int kt = (gw / NT64) % KT;
  const int e = gw / (NT64 * KT);
  const float* src = in + (size_t)e * K * N + (size_t)(kt * 64) * N + nT64 * 64 + lane;
  float c[64];
#pragma unroll
  for (int k = 0; k < 64; ++k) c[k] = src[(size_t)k * N];
  const int rowIn = ((nT64 & 1) << 6) + lane;           // row within 128-row chunk
  const int chunk = e * (N / 128) + (nT64 >> 1);
  ushort* dst = outp + ((size_t)chunk * KT + kt) * 8192 + (size_t)rowIn * 64;
  const int rs = rowIn & 7;
#pragma unroll
  for (int g = 0; g < 8; ++g) {
    ushort tmp[8];
#pragma unroll
    for (int j2 = 0; j2 < 8; ++j2) tmp[j2] = f2bf(c[g * 8 + j2]);
    *reinterpret_cast<uint4*>(dst + ((g ^ rs) << 3)) = *reinterpret_cast<const uint4*>(tmp);
  }
}

// ---------------- router (fused x->bf16 conversion) ----------------
__global__ void router_kernel(const float* __restrict__ x, const float* __restrict__ router,
                              int* __restrict__ cnt, int* __restrict__ list,
                              float* __restrict__ wa, ushort* __restrict__ xb) {
  __shared__ float rl[DM * NE];  // 32 KB
  int tid = threadIdx.x;
  for (int i = tid; i < DM * NE / 4; i += 256)
    reinterpret_cast<float4*>(rl)[i] = reinterpret_cast<const float4*>(router)[i];
  __syncthreads();
  int wave = tid >> 6, lane = tid & 63;
  int tok0 = blockIdx.x * 32 + wave * 8;
  for (int tI = 0; tI < 8; ++tI) {
    int tok = tok0 + tI;
    float acc[NE];
#pragma unroll
    for (int e2 = 0; e2 < NE; ++e2) acc[e2] = 0.f;
    const float4* xr = reinterpret_cast<const float4*>(x + (size_t)tok * DM);
    ushort xo[16];
#pragma unroll
    for (int c = 0; c < 4; ++c) {
      float4 v = xr[lane * 4 + c];
      int d = lane * 16 + c * 4;
      const float* vv = reinterpret_cast<const float*>(&v);
#pragma unroll
      for (int q = 0; q < 4; ++q) {
        float xv = vv[q];
        xo[c * 4 + q] = f2bf(xv);
#pragma unroll
        for (int e2 = 0; e2 < NE; ++e2) acc[e2] += xv * rl[(d + q) * NE + e2];
      }
    }
    *reinterpret_cast<uint4*>(xb + (size_t)tok * DM + lane * 16) =
        *reinterpret_cast<const uint4*>(&xo[0]);
    *reinterpret_cast<uint4*>(xb + (size_t)tok * DM + lane * 16 + 8) =
        *reinterpret_cast<const uint4*>(&xo[8]);
    for (int off = 32; off > 0; off >>= 1) {
#pragma unroll
      for (int e2 = 0; e2 < NE; ++e2) acc[e2] += __shfl_xor(acc[e2], off, 64);
    }
    if (lane == 0) {
      int i0 = 0; float v0 = acc[0];
#pragma unroll
      for (int e2 = 1; e2 < NE; ++e2) { if (acc[e2] > v0) { v0 = acc[e2]; i0 = e2; } }
      int i1 = -1; float v1 = -3.4e38f;
#pragma unroll
      for (int e2 = 0; e2 < NE; ++e2) { if (e2 != i0 && acc[e2] > v1) { v1 = acc[e2]; i1 = e2; } }
      float e1 = expf(v1 - v0);
      float w0 = 1.f / (1.f + e1);
      float w1 = e1 / (1.f + e1);
      int s0 = atomicAdd(&cnt[i0], 1);
      list[i0 * NTOK + s0] = tok * 2;
      wa[tok * 2] = w0;
      int s1 = atomicAdd(&cnt[i1], 1);
      list[i1 * NTOK + s1] = tok * 2 + 1;
      wa[tok * 2 + 1] = w1;
    }
  }
}

// ---------------- helpers ----------------
__device__ __forceinline__ void gl_lds16(unsigned long long g, void* s) {
  __builtin_amdgcn_global_load_lds(
      (const __attribute__((address_space(1))) unsigned int*)g,
      (__attribute__((address_space(3))) unsigned int*)s, 16, 0, 0);
}

#define WAITV0() asm volatile("s_waitcnt vmcnt(0)" ::: "memory")

__device__ __forceinline__ void BARRIER() {
  asm volatile("" ::: "memory");
  __builtin_amdgcn_s_barrier();
  asm volatile("" ::: "memory");
}

// ------------- R9-optimal sparse expert GEMM (128^2, 4 waves, 4 blk/CU) -------------
// Both passes measured AT the 16 B/cy/CU gl_lds staging-service invariant
// (9.9-10.0 TB/s chip-wide; verified across 7 schedule/tile variants) — core frozen.
template <int PASS>
__launch_bounds__(256, 4)
__global__ void moe_gemm(const ushort* __restrict__ Xb,
                         const ushort* __restrict__ Wp,
                         ushort* __restrict__ Hp,
                         const int* __restrict__ cnt,
                         const int* __restrict__ list,
                         const float* __restrict__ wa,
                         float* __restrict__ out) {
  constexpr int NK = 16;
  constexpr int NKP2 = 32;

  const int bid = blockIdx.x;
  const int xcd = bid & 7;
  const int j = bid >> 3;
  int t, nTile, kc;
  if (PASS == 1) { t = j >> 2; nTile = xcd * 4 + (j & 3); kc = 0; }
  else           { t = j >> 1; nTile = xcd; kc = j & 1; }
  // resolve (e, tTile) from cnt prefix
  int e = -1, tTile = 0, accT = 0;
#pragma unroll
  for (int ee = 0; ee < NE; ++ee) {
    int nt = (cnt[ee] + 127) >> 7;
    if (e < 0 && t < accT + nt) { e = ee; tTile = t - accT; }
    accT += nt;
  }
  if (e < 0) return;  // uniform exit before any barrier
  const int n = cnt[e];

  __shared__ __attribute__((aligned(16))) char As[16384];
  __shared__ __attribute__((aligned(16))) char Bs[16384];
  __shared__ int aL[128];
  __shared__ unsigned long long pL[128];

  const int tid = threadIdx.x;
  if (tid < 128) {
    int slot = tTile * 128 + tid;
    int sl = (slot < n) ? slot : (n - 1);
    int a = list[e * NTOK + sl];
    aL[tid] = (slot < n) ? a : -1;
    if (PASS == 1) pL[tid] = (unsigned long long)(Xb + (size_t)(a >> 1) * DM);
  }
  __syncthreads();

  const char* Bsrc = (const char*)Wp +
      ((size_t)(e * ((PASS == 1) ? 32 : 8) + nTile) * ((PASS == 1) ? 16 : 64) +
       (size_t)kc * 32) * 16384;
  const char* Asrc = nullptr;
  unsigned long long sA0[4];
  if constexpr (PASS == 1) {
    const int sr = tid >> 3, sc = (tid & 7) * 16;
#pragma unroll
    for (int jj = 0; jj < 4; ++jj) {
      int row = jj * 32 + sr;
      sA0[jj] = pL[row] + (unsigned)(sc ^ ((row & 7) << 4));  // source-swizzled gather
    }
  } else {
    Asrc = (const char*)Hp + ((size_t)t * 64 + kc * 32) * 16384;  // packed H, linear
  }

  const int wv = tid >> 6, lane = tid & 63;
  const int r0 = (wv >> 1) * 64, c0 = (wv & 1) * 64;

  f32x4 acc[4][4];
#pragma unroll
  for (int m = 0; m < 4; ++m)
#pragma unroll
    for (int nn = 0; nn < 4; ++nn) acc[m][nn] = (f32x4){0.f, 0.f, 0.f, 0.f};

  const int nkLoop = (PASS == 1) ? NK : NKP2;
  for (int kt = 0; kt < nkLoop; ++kt) {
    if constexpr (PASS == 1) {
#pragma unroll
      for (int jj = 0; jj < 4; ++jj)
        gl_lds16(sA0[jj] + (unsigned)kt * 128, As + jj * 4096 + tid * 16);
    } else {
#pragma unroll
      for (int jj = 0; jj < 4; ++jj)
        gl_lds16((unsigned long long)(Asrc + (size_t)kt * 16384 + jj * 4096 + tid * 16),
                 As + jj * 4096 + tid * 16);
    }
#pragma unroll
    for (int jj = 0; jj < 4; ++jj)
      gl_lds16((unsigned long long)(Bsrc + (size_t)kt * 16384 + jj * 4096 + tid * 16),
               Bs + jj * 4096 + tid * 16);
    WAITV0();
    BARRIER();
#pragma unroll
    for (int kk = 0; kk < 2; ++kk) {
      const int kb = kk * 64 + (lane >> 4) * 16;
      bf16x8 af[4], bfr[4];
#pragma unroll
      for (int m = 0; m < 4; ++m) {
        int row = r0 + m * 16 + (lane & 15);
        af[m] = *reinterpret_cast<const bf16x8*>(As + row * 128 + (kb ^ ((row & 7) << 4)));
      }
#pragma unroll
      for (int nn = 0; nn < 4; ++nn) {
        int row = c0 + nn * 16 + (lane & 15);
        bfr[nn] = *reinterpret_cast<const bf16x8*>(Bs + row * 128 + (kb ^ ((row & 7) << 4)));
      }
      __builtin_amdgcn_s_setprio(1);
#pragma unroll
      for (int m = 0; m < 4; ++m)
#pragma unroll
        for (int nn = 0; nn < 4; ++nn)
          acc[m][nn] = __builtin_amdgcn_mfma_f32_16x16x32_bf16(af[m], bfr[nn], acc[m][nn], 0, 0, 0);
      __builtin_amdgcn_s_setprio(0);
    }
    BARRIER();  // WAR before next stage overwrites
  }

  // epilogue — C/D layout: col = lane&15, row = (lane>>4)*4 + jr
#pragma unroll
  for (int m = 0; m < 4; ++m) {
#pragma unroll
    for (int jr = 0; jr < 4; ++jr) {
      int lr = r0 + m * 16 + (lane >> 4) * 4 + jr;
      if constexpr (PASS == 1) {
        // all rows written (padding rows dup last real; pass2 discards via aL<0)
#pragma unroll
        for (int nn = 0; nn < 4; ++nn) {
          int cg = nTile * 128 + c0 + nn * 16 + (lane & 15);
          float v = acc[m][nn][jr];
          size_t us = ((size_t)t * 64 + (cg >> 6)) * 8192 + (size_t)lr * 64 +
                      ((cg & 63) ^ ((lr & 7) << 3));
          Hp[us] = f2bf(v / (1.f + expf(-v)));  // swish, packed-swizzled H
        }
      } else {
        int a = aL[lr];
        if (a < 0) continue;
        float w = wa[a];
        int tok = a >> 1;
        float* orow = out + (size_t)tok * DM + nTile * 128 + c0 + (lane & 15);
#pragma unroll
        for (int nn = 0; nn < 4; ++nn)
          atomicAdd(&orow[nn * 16], w * acc[m][nn][jr]);  // 2 experts x 2 kc, commutative
      }
    }
  }
}

extern "C" void kernel_launch(void* const* d_in, const int* in_sizes, int n_in,
                              void* d_out, int out_size, void* d_ws, size_t ws_size,
                              hipStream_t stream) {
  const float* x = (const float*)d_in[0];
  const float* router = (const float*)d_in[1];
  const float* W1 = (const float*)d_in[2];
  const float* W2 = (const float*)d_in[3];
  float* out = (float*)d_out;
  char* ws = (char*)d_ws;

  // [0,80 MiB): Xb (16) + Wp1 (64) during pass1; Wp2 (64) aliases [0,64) after pass1
  // (stream is serial; R9/R19-verified through full graph timing).
  ushort* Xb  = (ushort*)(ws + 0);
  ushort* Wp1 = (ushort*)(ws + (size_t)16 * 1024 * 1024);
  ushort* Wp2 = (ushort*)(ws + 0);
  size_t off = (size_t)80 * 1024 * 1024;
  ushort* Hp = (ushort*)(ws + off); off += (size_t)MAXT * 64 * 16384;  // 142.6 MB
  int* cnt  = (int*)(ws + off); off += 1024;
  int* list = (int*)(ws + off); off += (size_t)NE * NTOK * 4;
  float* wa = (float*)(ws + off); off += (size_t)NTOK * 2 * 4;

  hipMemsetAsync(out, 0, (size_t)NTOK * DM * sizeof(float), stream);
  hipMemsetAsync(cnt, 0, NE * sizeof(int), stream);

  router_kernel<<<NTOK / 32, 256, 0, stream>>>(x, router, cnt, list, wa, Xb);
  // pack W1: (DFF/64)*(DM/64)*NE = 8192 waves -> 2048 blocks
  pack_w<DM, DFF><<<(DFF / 64) * (DM / 64) * NE / 4, 256, 0, stream>>>(W1, Wp1);

  // pass1: 32 nTiles c-fastest over 8 XCDs; grid 8*4*136 = 4352
  moe_gemm<1><<<8 * 4 * MAXT, 256, 0, stream>>>(Xb, Wp1, Hp, cnt, list, wa, out);

  pack_w<DFF, DM><<<(DM / 64) * (DFF / 64) * NE / 4, 256, 0, stream>>>(W2, Wp2);

  // pass2: 8 nTiles x kc-split 2; grid 8*2*136 = 2176
  moe_gemm<2><<<8 * 2 * MAXT, 256, 0, stream>>>(Xb, Wp2, Hp, cnt, list, wa, out);
}

// Round 21
// 669.347 us; speedup vs baseline: 1.0801x; 1.0801x over previous
//
#include <hip/hip_runtime.h>
#include <hip/hip_bf16.h>

#define NTOK 8192
#define DM 1024
#define DFF 4096
#define NE 8
#define MAXT 136  // max 128-row tiles: 16384/128 + 8 partials

typedef __attribute__((ext_vector_type(8))) short bf16x8;
typedef __attribute__((ext_vector_type(4))) float f32x4;

__device__ __forceinline__ ushort f2bf(float f) {
  __hip_bfloat16 h = __float2bfloat16(f);
  return *reinterpret_cast<ushort*>(&h);
}

// ---- pack W [e][K][N] fp32 -> Wp chunks keyed (e*(N/128)+nT)*(K/64)+kt of
// ---- [row128][64 ushort], swizzle baked: pos u holds col u^((row&7)<<3).
// ---- R19-validated LDS-transpose version (plain loads; NT loads/stores and the
// ---- zero-LDS wave-transpose both measured slower on gfx950 - R11/R17/R20).
template <int K, int N>
__global__ void pack_w(const float* __restrict__ in, ushort* __restrict__ outp) {
  __shared__ float t[64][129];
  const int e = blockIdx.z, nT = blockIdx.x, kt = blockIdx.y;
  const float* src = in + (size_t)e * K * N + (size_t)kt * 64 * N + (size_t)nT * 128;
  const int tid = threadIdx.x;
#pragma unroll
  for (int it = 0; it < 8; ++it) {
    int idx = it * 256 + tid;
    int kl = idx >> 5, n4 = idx & 31;
    f32x4 v = *reinterpret_cast<const f32x4*>(src + (size_t)kl * N + n4 * 4);
    t[kl][n4 * 4 + 0] = v.x; t[kl][n4 * 4 + 1] = v.y;
    t[kl][n4 * 4 + 2] = v.z; t[kl][n4 * 4 + 3] = v.w;
  }
  __syncthreads();
  const int row = tid >> 1, half = tid & 1;
  const int s = (row & 7) << 3;
  union { ushort us[32]; uint4 q[4]; } u;
#pragma unroll
  for (int k2 = 0; k2 < 32; ++k2) u.us[k2] = f2bf(t[(half * 32 + k2) ^ s][row]);
  ushort* dst = outp + ((size_t)(e * (N / 128) + nT) * (K / 64) + kt) * 8192 + row * 64 + half * 32;
  uint4* d4 = reinterpret_cast<uint4*>(dst);
  d4[0] = u.q[0]; d4[1] = u.q[1]; d4[2] = u.q[2]; d4[3] = u.q[3];
}

// ---------------- router (fused x->bf16 conversion) ----------------
__global__ void router_kernel(const float* __restrict__ x, const float* __restrict__ router,
                              int* __restrict__ cnt, int* __restrict__ list,
                              float* __restrict__ wa, ushort* __restrict__ xb) {
  __shared__ float rl[DM * NE];  // 32 KB
  int tid = threadIdx.x;
  for (int i = tid; i < DM * NE / 4; i += 256)
    reinterpret_cast<float4*>(rl)[i] = reinterpret_cast<const float4*>(router)[i];
  __syncthreads();
  int wave = tid >> 6, lane = tid & 63;
  int tok0 = blockIdx.x * 32 + wave * 8;
  for (int tI = 0; tI < 8; ++tI) {
    int tok = tok0 + tI;
    float acc[NE];
#pragma unroll
    for (int e2 = 0; e2 < NE; ++e2) acc[e2] = 0.f;
    const float4* xr = reinterpret_cast<const float4*>(x + (size_t)tok * DM);
    ushort xo[16];
#pragma unroll
    for (int c = 0; c < 4; ++c) {
      float4 v = xr[lane * 4 + c];
      int d = lane * 16 + c * 4;
      const float* vv = reinterpret_cast<const float*>(&v);
#pragma unroll
      for (int q = 0; q < 4; ++q) {
        float xv = vv[q];
        xo[c * 4 + q] = f2bf(xv);
#pragma unroll
        for (int e2 = 0; e2 < NE; ++e2) acc[e2] += xv * rl[(d + q) * NE + e2];
      }
    }
    *reinterpret_cast<uint4*>(xb + (size_t)tok * DM + lane * 16) =
        *reinterpret_cast<const uint4*>(&xo[0]);
    *reinterpret_cast<uint4*>(xb + (size_t)tok * DM + lane * 16 + 8) =
        *reinterpret_cast<const uint4*>(&xo[8]);
    for (int off = 32; off > 0; off >>= 1) {
#pragma unroll
      for (int e2 = 0; e2 < NE; ++e2) acc[e2] += __shfl_xor(acc[e2], off, 64);
    }
    if (lane == 0) {
      int i0 = 0; float v0 = acc[0];
#pragma unroll
      for (int e2 = 1; e2 < NE; ++e2) { if (acc[e2] > v0) { v0 = acc[e2]; i0 = e2; } }
      int i1 = -1; float v1 = -3.4e38f;
#pragma unroll
      for (int e2 = 0; e2 < NE; ++e2) { if (e2 != i0 && acc[e2] > v1) { v1 = acc[e2]; i1 = e2; } }
      float e1 = expf(v1 - v0);
      float w0 = 1.f / (1.f + e1);
      float w1 = e1 / (1.f + e1);
      int s0 = atomicAdd(&cnt[i0], 1);
      list[i0 * NTOK + s0] = tok * 2;
      wa[tok * 2] = w0;
      int s1 = atomicAdd(&cnt[i1], 1);
      list[i1 * NTOK + s1] = tok * 2 + 1;
      wa[tok * 2 + 1] = w1;
    }
  }
}

// ---------------- helpers ----------------
__device__ __forceinline__ void gl_lds16(unsigned long long g, void* s) {
  __builtin_amdgcn_global_load_lds(
      (const __attribute__((address_space(1))) unsigned int*)g,
      (__attribute__((address_space(3))) unsigned int*)s, 16, 0, 0);
}

#define WAITV0() asm volatile("s_waitcnt vmcnt(0)" ::: "memory")

__device__ __forceinline__ void BARRIER() {
  asm volatile("" ::: "memory");
  __builtin_amdgcn_s_barrier();
  asm volatile("" ::: "memory");
}

// ------------- R9/R19-optimal sparse expert GEMM (128^2, 4 waves, 4 blk/CU) -------------
// Single-buffer 33.5 KB LDS; body: stage -> vmcnt(0) -> barrier -> compute -> barrier.
// Both passes measured AT the 16 B/cy/CU gl_lds staging-service invariant
// (~10 TB/s chip-wide; confirmed across 8 schedule/tile variants) — core frozen.
template <int PASS>
__launch_bounds__(256, 4)
__global__ void moe_gemm(const ushort* __restrict__ Xb,
                         const ushort* __restrict__ Wp,
                         ushort* __restrict__ Hp,
                         const int* __restrict__ cnt,
                         const int* __restrict__ list,
                         const float* __restrict__ wa,
                         float* __restrict__ out) {
  constexpr int NK = 16;
  constexpr int NKP2 = 32;

  const int bid = blockIdx.x;
  const int xcd = bid & 7;
  const int j = bid >> 3;
  int t, nTile, kc;
  if (PASS == 1) { t = j >> 2; nTile = xcd * 4 + (j & 3); kc = 0; }
  else           { t = j >> 1; nTile = xcd; kc = j & 1; }
  // resolve (e, tTile) from cnt prefix
  int e = -1, tTile = 0, accT = 0;
#pragma unroll
  for (int ee = 0; ee < NE; ++ee) {
    int nt = (cnt[ee] + 127) >> 7;
    if (e < 0 && t < accT + nt) { e = ee; tTile = t - accT; }
    accT += nt;
  }
  if (e < 0) return;  // uniform exit before any barrier
  const int n = cnt[e];

  __shared__ __attribute__((aligned(16))) char As[16384];
  __shared__ __attribute__((aligned(16))) char Bs[16384];
  __shared__ int aL[128];
  __shared__ unsigned long long pL[128];

  const int tid = threadIdx.x;
  if (tid < 128) {
    int slot = tTile * 128 + tid;
    int sl = (slot < n) ? slot : (n - 1);
    int a = list[e * NTOK + sl];
    aL[tid] = (slot < n) ? a : -1;
    if (PASS == 1) pL[tid] = (unsigned long long)(Xb + (size_t)(a >> 1) * DM);
  }
  __syncthreads();

  const char* Bsrc = (const char*)Wp +
      ((size_t)(e * ((PASS == 1) ? 32 : 8) + nTile) * ((PASS == 1) ? 16 : 64) +
       (size_t)kc * 32) * 16384;
  const char* Asrc = nullptr;
  unsigned long long sA0[4];
  if constexpr (PASS == 1) {
    const int sr = tid >> 3, sc = (tid & 7) * 16;
#pragma unroll
    for (int jj = 0; jj < 4; ++jj) {
      int row = jj * 32 + sr;
      sA0[jj] = pL[row] + (unsigned)(sc ^ ((row & 7) << 4));  // source-swizzled gather
    }
  } else {
    Asrc = (const char*)Hp + ((size_t)t * 64 + kc * 32) * 16384;  // packed H, linear
  }

  const int wv = tid >> 6, lane = tid & 63;
  const int r0 = (wv >> 1) * 64, c0 = (wv & 1) * 64;

  f32x4 acc[4][4];
#pragma unroll
  for (int m = 0; m < 4; ++m)
#pragma unroll
    for (int nn = 0; nn < 4; ++nn) acc[m][nn] = (f32x4){0.f, 0.f, 0.f, 0.f};

  const int nkLoop = (PASS == 1) ? NK : NKP2;
  for (int kt = 0; kt < nkLoop; ++kt) {
    if constexpr (PASS == 1) {
#pragma unroll
      for (int jj = 0; jj < 4; ++jj)
        gl_lds16(sA0[jj] + (unsigned)kt * 128, As + jj * 4096 + tid * 16);
    } else {
#pragma unroll
      for (int jj = 0; jj < 4; ++jj)
        gl_lds16((unsigned long long)(Asrc + (size_t)kt * 16384 + jj * 4096 + tid * 16),
                 As + jj * 4096 + tid * 16);
    }
#pragma unroll
    for (int jj = 0; jj < 4; ++jj)
      gl_lds16((unsigned long long)(Bsrc + (size_t)kt * 16384 + jj * 4096 + tid * 16),
               Bs + jj * 4096 + tid * 16);
    WAITV0();
    BARRIER();
#pragma unroll
    for (int kk = 0; kk < 2; ++kk) {
      const int kb = kk * 64 + (lane >> 4) * 16;
      bf16x8 af[4], bfr[4];
#pragma unroll
      for (int m = 0; m < 4; ++m) {
        int row = r0 + m * 16 + (lane & 15);
        af[m] = *reinterpret_cast<const bf16x8*>(As + row * 128 + (kb ^ ((row & 7) << 4)));
      }
#pragma unroll
      for (int nn = 0; nn < 4; ++nn) {
        int row = c0 + nn * 16 + (lane & 15);
        bfr[nn] = *reinterpret_cast<const bf16x8*>(Bs + row * 128 + (kb ^ ((row & 7) << 4)));
      }
      __builtin_amdgcn_s_setprio(1);
#pragma unroll
      for (int m = 0; m < 4; ++m)
#pragma unroll
        for (int nn = 0; nn < 4; ++nn)
          acc[m][nn] = __builtin_amdgcn_mfma_f32_16x16x32_bf16(af[m], bfr[nn], acc[m][nn], 0, 0, 0);
      __builtin_amdgcn_s_setprio(0);
    }
    BARRIER();  // WAR before next stage overwrites
  }

  // epilogue — C/D layout: col = lane&15, row = (lane>>4)*4 + jr
#pragma unroll
  for (int m = 0; m < 4; ++m) {
#pragma unroll
    for (int jr = 0; jr < 4; ++jr) {
      int lr = r0 + m * 16 + (lane >> 4) * 4 + jr;
      if constexpr (PASS == 1) {
        // all rows written (padding rows dup last real; pass2 discards via aL<0)
#pragma unroll
        for (int nn = 0; nn < 4; ++nn) {
          int cg = nTile * 128 + c0 + nn * 16 + (lane & 15);
          float v = acc[m][nn][jr];
          size_t us = ((size_t)t * 64 + (cg >> 6)) * 8192 + (size_t)lr * 64 +
                      ((cg & 63) ^ ((lr & 7) << 3));
          Hp[us] = f2bf(v / (1.f + expf(-v)));  // swish, packed-swizzled H
        }
      } else {
        int a = aL[lr];
        if (a < 0) continue;
        float w = wa[a];
        int tok = a >> 1;
        float* orow = out + (size_t)tok * DM + nTile * 128 + c0 + (lane & 15);
#pragma unroll
        for (int nn = 0; nn < 4; ++nn)
          atomicAdd(&orow[nn * 16], w * acc[m][nn][jr]);  // 2 experts x 2 kc, commutative
      }
    }
  }
}

extern "C" void kernel_launch(void* const* d_in, const int* in_sizes, int n_in,
                              void* d_out, int out_size, void* d_ws, size_t ws_size,
                              hipStream_t stream) {
  const float* x = (const float*)d_in[0];
  const float* router = (const float*)d_in[1];
  const float* W1 = (const float*)d_in[2];
  const float* W2 = (const float*)d_in[3];
  float* out = (float*)d_out;
  char* ws = (char*)d_ws;

  // [0,80 MiB): Xb (16) + Wp1 (64) during pass1; Wp2 (64) aliases [0,64) after pass1
  // (stream is serial; R9/R19-verified through full graph timing).
  ushort* Xb  = (ushort*)(ws + 0);
  ushort* Wp1 = (ushort*)(ws + (size_t)16 * 1024 * 1024);
  ushort* Wp2 = (ushort*)(ws + 0);
  size_t off = (size_t)80 * 1024 * 1024;
  ushort* Hp = (ushort*)(ws + off); off += (size_t)MAXT * 64 * 16384;  // 142.6 MB
  int* cnt  = (int*)(ws + off); off += 1024;
  int* list = (int*)(ws + off); off += (size_t)NE * NTOK * 4;
  float* wa = (float*)(ws + off); off += (size_t)NTOK * 2 * 4;

  hipMemsetAsync(out, 0, (size_t)NTOK * DM * sizeof(float), stream);
  hipMemsetAsync(cnt, 0, NE * sizeof(int), stream);

  pack_w<DM, DFF><<<dim3(DFF / 128, DM / 64, NE), 256, 0, stream>>>(W1, Wp1);
  router_kernel<<<NTOK / 32, 256, 0, stream>>>(x, router, cnt, list, wa, Xb);

  // pass1: 32 nTiles c-fastest over 8 XCDs; grid 8*4*136 = 4352
  moe_gemm<1><<<8 * 4 * MAXT, 256, 0, stream>>>(Xb, Wp1, Hp, cnt, list, wa, out);

  pack_w<DFF, DM><<<dim3(DM / 128, DFF / 64, NE), 256, 0, stream>>>(W2, Wp2);

  // pass2: 8 nTiles x kc-split 2; grid 8*2*136 = 2176
  moe_gemm<2><<<8 * 2 * MAXT, 256, 0, stream>>>(Xb, Wp2, Hp, cnt, list, wa, out);
}